// Round 2
// baseline (115.429 us; speedup 1.0000x reference)
//
#include <hip/hip_runtime.h>
#include <hip/hip_bf16.h>
#include <stdint.h>

#define AS1 __attribute__((address_space(1)))
#define AS3 __attribute__((address_space(3)))

typedef __attribute__((ext_vector_type(8))) short bf16x8_t;
typedef __attribute__((ext_vector_type(4))) float f32x4_t;

#define DDIM 1024
#define WT_ELEMS ((size_t)DDIM * DDIM)   // 1 Mi bf16 = 2 MiB
#define XB_ELEMS ((size_t)8192 * DDIM)   // 8 Mi bf16 = 16 MiB

// fp32 -> bf16 round-to-nearest-even (truncation bias over K=1024 would eat
// most of the absmax budget).
static __device__ inline ushort f32_to_bf16_rne(float f) {
  union { float f; uint32_t u; } v;
  v.f = f;
  v.u += 0x7FFFu + ((v.u >> 16) & 1u);
  return (ushort)(v.u >> 16);
}

// ---------------------------------------------------------------------------
// Fused one-time prep (single launch):
//   blocks [0,256):    Wt[n][k] = bf16(W[k][n])  (64x64 tiles, LDS transpose)
//   blocks [256,4352): Xb = bf16(X)              (streaming convert)
// ---------------------------------------------------------------------------
__global__ __launch_bounds__(256) void prep(const float* __restrict__ W,
                                            ushort* __restrict__ Wt,
                                            const float* __restrict__ X,
                                            ushort* __restrict__ Xb) {
  if (blockIdx.x < 256) {
    __shared__ float tile[64][65];
    const int t  = threadIdx.x;
    const int bk = blockIdx.x & 15;
    const int bn = blockIdx.x >> 4;
#pragma unroll
    for (int s = 0; s < 4; ++s) {
      const int slot = (s << 8) + t;
      const int r    = slot >> 4;
      const int c4   = (slot & 15) << 2;
      const float4 v = *(const float4*)(W + (size_t)(bk * 64 + r) * DDIM + bn * 64 + c4);
      tile[r][c4 + 0] = v.x; tile[r][c4 + 1] = v.y;
      tile[r][c4 + 2] = v.z; tile[r][c4 + 3] = v.w;
    }
    __syncthreads();
#pragma unroll
    for (int s = 0; s < 2; ++s) {
      const int slot = (s << 8) + t;
      const int n    = slot >> 3;
      const int k8   = (slot & 7) << 3;
      union { ushort h[8]; uint4 u; } tmp;
#pragma unroll
      for (int j = 0; j < 8; ++j) tmp.h[j] = f32_to_bf16_rne(tile[k8 + j][n]);
      *(uint4*)(Wt + (size_t)(bn * 64 + n) * DDIM + bk * 64 + k8) = tmp.u;
    }
  } else {
    const size_t i = ((size_t)(blockIdx.x - 256) * 256 + threadIdx.x) << 3;
    const float4 v0 = *(const float4*)(X + i);
    const float4 v1 = *(const float4*)(X + i + 4);
    union { ushort h[8]; uint4 u; } o;
    o.h[0] = f32_to_bf16_rne(v0.x); o.h[1] = f32_to_bf16_rne(v0.y);
    o.h[2] = f32_to_bf16_rne(v0.z); o.h[3] = f32_to_bf16_rne(v0.w);
    o.h[4] = f32_to_bf16_rne(v1.x); o.h[5] = f32_to_bf16_rne(v1.y);
    o.h[6] = f32_to_bf16_rne(v1.z); o.h[7] = f32_to_bf16_rne(v1.w);
    *(uint4*)(Xb + i) = o.u;
  }
}

// ---------------------------------------------------------------------------
// Main GEMM: C[fp32 8192x1024] = Xb * Wt^T.
// 256 threads (4 waves, 2x2 -> 64x64 wave tiles), 128x128 tile.
//
// ROUND-6 CHANGE (true T3/T4 depth): round-5's counted vmcnt was neutral
// because a 2-buffer ring has prefetch distance = 1 iteration (~300-350
// cyc) < L3 load latency (~400-600 cyc) -- the wait just moved from
// vmcnt(0) to vmcnt(8). This version shrinks the staging granule to
// BK=32 and runs a 4-DEEP LDS RING (4 x (8KB A + 8KB B) = 64 KB, still
// 2 blocks/CU): stage i+3 is issued while stage i computes, so loads get
// ~3 stage-windows (~500-700 cyc) of flight time. vmcnt(12) retires
// exactly stage i's 4 loads; 12 stay in flight across every barrier.
//
// Swizzle (rule #21, both-sides-same-involution): rows are now 64 B =
// 4 chunks of 16 B. Stored slot s of row r holds global chunk s^f(r),
// f(r) = (r>>1)&3. Read of chunk kc -> slot kc^f(r). Bank starts
// 16*(r&1) + 4*(kc^f(r)) cover all 8 distinct 16B-slots over 8 rows ->
// 2-way on ds_read_b128 (free, m136). global_load_lds dest stays linear
// (base + lane*16); the source address carries the permutation.
//
// Barrier #1 (pre-compute): each wave waits its OWN vmcnt before
// s_barrier, so after it all waves' stage-i data is in LDS.
// Barrier #2 (post-compute): all ds_reads of buf i&3 are consumed by
// MFMAs before it (compiler lgkmcnt), so iter i+1 may overwrite buf i&3.
// ---------------------------------------------------------------------------
__global__ __launch_bounds__(256, 2) void gemm_bb(const ushort* __restrict__ Xb,
                                                  const ushort* __restrict__ Wt,
                                                  float* __restrict__ C) {
  __shared__ __align__(16) ushort As[4][128 * 32];  // 4 x 8 KB
  __shared__ __align__(16) ushort Bs[4][128 * 32];  // 4 x 8 KB

  const int t    = threadIdx.x;
  const int wave = t >> 6;
  const int lane = t & 63;
  const int m0 = blockIdx.x * 128;
  const int n0 = blockIdx.y * 128;

  // Staging map: thread t covers row sr = t>>2 (0..63) of each 64-row half
  // (2 halves per 128-row tile), slot s = t&3, swizzled global chunk
  // sc = s ^ ((sr>>1)&3). (sr+64)>>1 & 3 == (sr>>1)&3, so one sc serves
  // both halves. LDS dest is linear: addr(t) = t*16 within the half.
  const int sr = t >> 2;
  const int sc = (t & 3) ^ ((sr >> 1) & 3);
  const ushort* aB = Xb + (size_t)(m0 + sr) * DDIM + (sc << 3);
  const ushort* bB = Wt + (size_t)(n0 + sr) * DDIM + (sc << 3);

  AS3 char* lA = (AS3 char*)&As[0][0];
  AS3 char* lB = (AS3 char*)&Bs[0][0];
  const int woff = wave << 10;

  // Wave tile: 64x64, 4x4 frags of 16x16x32.
  const int wr = (wave >> 1) << 6;
  const int wc = (wave & 1) << 6;
  const int fr = lane & 15;
  const int fq = lane >> 4;

  f32x4_t acc[4][4] = {};

  // Issue stage st (K cols [st*32, st*32+32)) into ring buffer st&3.
  // 4 global_load_lds per thread (2 halves x {A,B}).
  auto issue = [&](int st) {
    const int p = st & 3;
    const ushort* a = aB + (st << 5);
    const ushort* b = bB + (st << 5);
    AS3 char* dA = lA + (p << 13) + woff;
    AS3 char* dB = lB + (p << 13) + woff;
#pragma unroll
    for (int j = 0; j < 2; ++j) {
      __builtin_amdgcn_global_load_lds((const AS1 void*)(a + (size_t)(j << 6) * DDIM),
                                       (AS3 void*)(dA + (j << 12)), 16, 0, 0);
      __builtin_amdgcn_global_load_lds((const AS1 void*)(b + (size_t)(j << 6) * DDIM),
                                       (AS3 void*)(dB + (j << 12)), 16, 0, 0);
    }
  };

  // One BK=32 stage: 8 ds_read_b128 + 16 MFMA per wave.
  auto compute = [&](int p) {
    const ushort* Ab = &As[p][0];
    const ushort* Bb = &Bs[p][0];
    bf16x8_t af[4], bfr[4];
#pragma unroll
    for (int mi = 0; mi < 4; ++mi) {
      const int r = wr + (mi << 4) + fr;
      af[mi] = *(const bf16x8_t*)&Ab[(r << 5) + ((fq ^ ((r >> 1) & 3)) << 3)];
    }
#pragma unroll
    for (int ni = 0; ni < 4; ++ni) {
      const int r = wc + (ni << 4) + fr;
      bfr[ni] = *(const bf16x8_t*)&Bb[(r << 5) + ((fq ^ ((r >> 1) & 3)) << 3)];
    }
#pragma unroll
    for (int mi = 0; mi < 4; ++mi)
#pragma unroll
      for (int ni = 0; ni < 4; ++ni)
        acc[mi][ni] = __builtin_amdgcn_mfma_f32_16x16x32_bf16(af[mi], bfr[ni], acc[mi][ni], 0, 0, 0);
  };

  // Prologue: fill 3 stages of the ring; guarantee stage 0 landed.
  issue(0);
  issue(1);
  issue(2);
  asm volatile("s_waitcnt vmcnt(8)\n\ts_barrier" ::: "memory");

  // Main loop: 32 stages of BK=32. Stages 0..28 issue 3 ahead.
  for (int i = 0; i < 29; ++i) {
    issue(i + 3);
    // Retire exactly stage i's 4 loads; stages i+1..i+3 (12) stay in flight.
    // (At i==0 this is a no-op wait; stage 0 is covered by the prologue.)
    asm volatile("s_waitcnt vmcnt(12)\n\ts_barrier" ::: "memory");
    compute(i & 3);
    // All waves' ds_reads of buf i&3 done -> iter i+1 may overwrite it.
    asm volatile("s_barrier" ::: "memory");
  }
  // Tail: drain stages 29,30,31 (no more issues, no more LDS writes).
  asm volatile("s_waitcnt vmcnt(8)\n\ts_barrier" ::: "memory");
  compute(1);
  asm volatile("s_waitcnt vmcnt(4)\n\ts_barrier" ::: "memory");
  compute(2);
  asm volatile("s_waitcnt vmcnt(0)\n\ts_barrier" ::: "memory");
  compute(3);

  // Epilogue. C/D layout: col = lane&15, row = (lane>>4)*4 + reg.
#pragma unroll
  for (int mi = 0; mi < 4; ++mi) {
#pragma unroll
    for (int r = 0; r < 4; ++r) {
      const int row = m0 + wr + (mi << 4) + (fq << 2) + r;
      float* crow = C + (size_t)row * DDIM + n0 + wc + fr;
#pragma unroll
      for (int ni = 0; ni < 4; ++ni)
        crow[ni << 4] = acc[mi][ni][r];
    }
  }
}

// ---------------------------------------------------------------------------
// Fallback GEMM (round-2, known correct) if ws can't hold Wt + Xb.
// ---------------------------------------------------------------------------
__global__ __launch_bounds__(256) void gemm_xw(const float* __restrict__ X,
                                               const ushort* __restrict__ Wt,
                                               float* __restrict__ C) {
  __shared__ __align__(16) ushort As[128 * 32];
  __shared__ __align__(16) ushort Bs[128 * 32];
  const int t    = threadIdx.x;
  const int wave = t >> 6;
  const int lane = t & 63;
  const int m0 = blockIdx.x * 128;
  const int n0 = blockIdx.y * 128;
  const int srow  = (wave << 4) + (lane >> 2);
  const int skcol = (lane & 3) << 3;
  const ushort* bptr0 = Wt + (size_t)(n0 + srow) * DDIM + skcol;
  const ushort* bptr1 = Wt + (size_t)(n0 + 64 + srow) * DDIM + skcol;
  const int ar = t >> 2;
  const int ak = (t & 3) << 3;
  const float* aptr0 = X + (size_t)(m0 + ar) * DDIM + ak;
  const float* aptr1 = X + (size_t)(m0 + 64 + ar) * DDIM + ak;
  ushort* asw0 = &As[(ar << 5) + ak];
  ushort* asw1 = &As[((ar + 64) << 5) + ak];
  const int wr = (wave >> 1) << 6;
  const int wc = (wave & 1) << 6;
  const int fr = lane & 15;
  const int fq = lane >> 4;
  f32x4_t acc[4][4] = {};
  AS3 char* ldsB = (AS3 char*)Bs;
  const int woff = wave << 10;
  for (int kt = 0; kt < DDIM; kt += 32) {
    const float4 a00 = *(const float4*)(aptr0);
    const float4 a01 = *(const float4*)(aptr0 + 4);
    const float4 a10 = *(const float4*)(aptr1);
    const float4 a11 = *(const float4*)(aptr1 + 4);
    aptr0 += 32; aptr1 += 32;
    __syncthreads();
    __builtin_amdgcn_global_load_lds((const AS1 void*)bptr0, (AS3 void*)(ldsB + woff),        16, 0, 0);
    __builtin_amdgcn_global_load_lds((const AS1 void*)bptr1, (AS3 void*)(ldsB + 4096 + woff), 16, 0, 0);
    bptr0 += 32; bptr1 += 32;
    union { ushort h[8]; bf16x8_t v; } c0, c1;
    c0.h[0] = f32_to_bf16_rne(a00.x); c0.h[1] = f32_to_bf16_rne(a00.y);
    c0.h[2] = f32_to_bf16_rne(a00.z); c0.h[3] = f32_to_bf16_rne(a00.w);
    c0.h[4] = f32_to_bf16_rne(a01.x); c0.h[5] = f32_to_bf16_rne(a01.y);
    c0.h[6] = f32_to_bf16_rne(a01.z); c0.h[7] = f32_to_bf16_rne(a01.w);
    c1.h[0] = f32_to_bf16_rne(a10.x); c1.h[1] = f32_to_bf16_rne(a10.y);
    c1.h[2] = f32_to_bf16_rne(a10.z); c1.h[3] = f32_to_bf16_rne(a10.w);
    c1.h[4] = f32_to_bf16_rne(a11.x); c1.h[5] = f32_to_bf16_rne(a11.y);
    c1.h[6] = f32_to_bf16_rne(a11.z); c1.h[7] = f32_to_bf16_rne(a11.w);
    *(bf16x8_t*)asw0 = c0.v;
    *(bf16x8_t*)asw1 = c1.v;
    __syncthreads();
    bf16x8_t af[4], bfr[4];
#pragma unroll
    for (int mi = 0; mi < 4; ++mi)
      af[mi] = *(const bf16x8_t*)&As[((wr + (mi << 4) + fr) << 5) + (fq << 3)];
#pragma unroll
    for (int ni = 0; ni < 4; ++ni)
      bfr[ni] = *(const bf16x8_t*)&Bs[((wc + (ni << 4) + fr) << 5) + (fq << 3)];
#pragma unroll
    for (int mi = 0; mi < 4; ++mi)
#pragma unroll
      for (int ni = 0; ni < 4; ++ni)
        acc[mi][ni] = __builtin_amdgcn_mfma_f32_16x16x32_bf16(af[mi], bfr[ni], acc[mi][ni], 0, 0, 0);
  }
#pragma unroll
  for (int mi = 0; mi < 4; ++mi)
#pragma unroll
    for (int r = 0; r < 4; ++r) {
      const int row = m0 + wr + (mi << 4) + (fq << 2) + r;
      float* crow = C + (size_t)row * DDIM + n0 + wc + fr;
#pragma unroll
      for (int ni = 0; ni < 4; ++ni)
        crow[ni << 4] = acc[mi][ni][r];
    }
}

// ---------------------------------------------------------------------------
// softmax over the size-1 sequence axis == 1.0 exactly -> out = x @ kernel[2].
// ---------------------------------------------------------------------------
extern "C" void kernel_launch(void* const* d_in, const int* in_sizes, int n_in,
                              void* d_out, int out_size, void* d_ws, size_t ws_size,
                              hipStream_t stream) {
  const float* x    = (const float*)d_in[0];
  const float* kern = (const float*)d_in[1];
  const float* W = kern + (size_t)2 * DDIM * DDIM;  // kernel[2] — V projection
  ushort* Wt = (ushort*)d_ws;
  const int M = in_sizes[0] / DDIM;  // 8192

  if (ws_size >= (WT_ELEMS + XB_ELEMS) * sizeof(ushort)) {
    ushort* Xb = (ushort*)d_ws + WT_ELEMS;
    const unsigned cvt_blocks = (unsigned)((size_t)M * DDIM / 8 / 256);
    prep<<<256 + cvt_blocks, 256, 0, stream>>>(W, Wt, x, Xb);
    gemm_bb<<<dim3(M / 128, DDIM / 128), 256, 0, stream>>>(Xb, Wt, (float*)d_out);
  } else {
    prep<<<256, 256, 0, stream>>>(W, Wt, x, (ushort*)nullptr);
    gemm_xw<<<dim3(M / 128, DDIM / 128), 256, 0, stream>>>(x, Wt, (float*)d_out);
  }
}

// Round 3
// 114.364 us; speedup vs baseline: 1.0093x; 1.0093x over previous
//
#include <hip/hip_runtime.h>
#include <hip/hip_bf16.h>
#include <stdint.h>

#define AS1 __attribute__((address_space(1)))
#define AS3 __attribute__((address_space(3)))

typedef __attribute__((ext_vector_type(8))) short bf16x8_t;
typedef __attribute__((ext_vector_type(4))) float f32x4_t;

#define DDIM 1024
#define WT_ELEMS ((size_t)DDIM * DDIM)   // 1 Mi bf16 = 2 MiB

// fp32 -> bf16 round-to-nearest-even (software path, used in transpose_w).
static __device__ inline ushort f32_to_bf16_rne(float f) {
  union { float f; uint32_t u; } v;
  v.f = f;
  v.u += 0x7FFFu + ((v.u >> 16) & 1u);
  return (ushort)(v.u >> 16);
}

// ---------------------------------------------------------------------------
// One-time transpose+convert: Wt[n][k] = bf16(W[k][n]), W fp32 1024x1024.
// 256 blocks, ~6 MiB traffic -> ~2-3 us. (X is no longer pre-converted:
// round-7 folds A's fp32->bf16 into the GEMM staging, deleting the 48 MiB
// convert_x stream.)
// ---------------------------------------------------------------------------
__global__ __launch_bounds__(256) void transpose_w(const float* __restrict__ W,
                                                   ushort* __restrict__ Wt) {
  __shared__ float tile[64][65];
  const int t  = threadIdx.x;
  const int bk = blockIdx.x;
  const int bn = blockIdx.y;
#pragma unroll
  for (int s = 0; s < 4; ++s) {
    const int slot = (s << 8) + t;
    const int r    = slot >> 4;
    const int c4   = (slot & 15) << 2;
    const float4 v = *(const float4*)(W + (size_t)(bk * 64 + r) * DDIM + bn * 64 + c4);
    tile[r][c4 + 0] = v.x; tile[r][c4 + 1] = v.y;
    tile[r][c4 + 2] = v.z; tile[r][c4 + 3] = v.w;
  }
  __syncthreads();
#pragma unroll
  for (int s = 0; s < 2; ++s) {
    const int slot = (s << 8) + t;
    const int n    = slot >> 3;
    const int k8   = (slot & 7) << 3;
    union { ushort h[8]; uint4 u; } tmp;
#pragma unroll
    for (int j = 0; j < 8; ++j) tmp.h[j] = f32_to_bf16_rne(tile[k8 + j][n]);
    *(uint4*)(Wt + (size_t)(bn * 64 + n) * DDIM + bk * 64 + k8) = tmp.u;
  }
}

// ---------------------------------------------------------------------------
// Main GEMM: C[fp32 8192x1024] = bf16(X) * Wt^T, conversion fused into
// A-staging.
//
// ROUND-7: revert to the round-5 (best, 110.6) gemm schedule -- 128x128
// tile, BK=64, 2-deep ring, 2 barriers/iter, counted vmcnt -- round-6's
// 4-deep/BK=32 ring regressed (+4.8 us: 2x barrier count dominated).
// Change here is the A PATH ONLY: A is reg-staged from fp32 X
// (global_load_dwordx4 -> v_cvt_pk_bf16_f32 -> swizzled ds_write_b128),
// B stays on global_load_lds. This deletes the separate convert_x pass
// (48 MiB of stream traffic, ~8 us).
//
// Staging maps (rule #21 -- same involution on write & read):
//   B (gload_lds, LDS dest forced linear): global source pre-swizzled,
//     thread t covers row sr=t>>3 of each 32-row band, chunk sc=(t&7)^(sr&7).
//   A (reg-staged, we control the LDS write addr): global source LINEAR
//     (fully coalesced), chunk gc=t&7, row sr=t>>3 (+32j); LDS write slot
//     gc^(sr&7). Read side (both A and B): slot kc^(r&7). Bank-uniform:
//     per ds_write_b128, 8 rows x 8 slots cover all 32 banks evenly.
//
// Pipeline per iter i (T14 issue-early/write-late):
//   loadA(i+1) 8x dwordx4 -> regs; issueB(i+1) 4x gload_lds    [newest 12]
//   s_waitcnt vmcnt(12); s_barrier     -- retires exactly B(i)
//   compute(i)                          -- 16 ds_read_b128 + 32 MFMA /wave
//   cvt_pk + ds_write A(i+1) -> buf p^1 -- compiler vmcnt(4) retires A(i+1),
//                                          leaves B(i+1) in flight
//   s_waitcnt lgkmcnt(0); s_barrier    -- A writes visible; buf p reads done
// ---------------------------------------------------------------------------
__global__ __launch_bounds__(256, 2) void gemm_fa(const float* __restrict__ X,
                                                  const ushort* __restrict__ Wt,
                                                  float* __restrict__ C) {
  __shared__ __align__(16) ushort As[2][128 * 64];  // 2 x 16 KB
  __shared__ __align__(16) ushort Bs[2][128 * 64];  // 2 x 16 KB

  const int t    = threadIdx.x;
  const int wave = t >> 6;
  const int lane = t & 63;
  const int m0 = blockIdx.x * 128;
  const int n0 = blockIdx.y * 128;

  const int sr = t >> 3;          // row 0..31 within each 32-row band
  const int gc = t & 7;           // A: linear global chunk (coalesced)
  const int sc = gc ^ (sr & 7);   // B: pre-swizzled global chunk
  const int slotA = sc;           // A LDS write slot = gc ^ (sr&7) (same value)

  const float*  aB = X  + (size_t)(m0 + sr) * DDIM + (gc << 3);
  const ushort* bB = Wt + (size_t)(n0 + sr) * DDIM + (sc << 3);

  AS3 char* lB = (AS3 char*)&Bs[0][0];
  const int woff = wave << 10;

  // Wave tile: 64x64, 4x4 frags of 16x16x32.
  const int wr = (wave >> 1) << 6;
  const int wc = (wave & 1) << 6;
  const int fr = lane & 15;
  const int fq = lane >> 4;

  f32x4_t acc[4][4] = {};

  float4 av[8];  // A fp32 in flight: 4 bands x 8 floats

  auto loadA = [&](int kt) {
    const float* a = aB + kt;
#pragma unroll
    for (int j = 0; j < 4; ++j) {
      av[2 * j + 0] = *(const float4*)(a + (size_t)(j << 5) * DDIM);
      av[2 * j + 1] = *(const float4*)(a + (size_t)(j << 5) * DDIM + 4);
    }
  };

  auto issueB = [&](int kt, int p) {
    const ushort* b = bB + kt;
    AS3 char* dB = lB + (p << 14) + woff;
#pragma unroll
    for (int j = 0; j < 4; ++j) {
      __builtin_amdgcn_global_load_lds((const AS1 void*)(b + (size_t)(j << 5) * DDIM),
                                       (AS3 void*)(dB + (j << 12)), 16, 0, 0);
    }
  };

  // Convert the 32 staged fp32 to bf16 (HW packed RNE) and write swizzled.
  auto writeA = [&](int pn) {
#pragma unroll
    for (int j = 0; j < 4; ++j) {
      const float4 u0 = av[2 * j + 0];
      const float4 u1 = av[2 * j + 1];
      uint4 w;
      asm("v_cvt_pk_bf16_f32 %0, %1, %2" : "=v"(w.x) : "v"(u0.x), "v"(u0.y));
      asm("v_cvt_pk_bf16_f32 %0, %1, %2" : "=v"(w.y) : "v"(u0.z), "v"(u0.w));
      asm("v_cvt_pk_bf16_f32 %0, %1, %2" : "=v"(w.z) : "v"(u1.x), "v"(u1.y));
      asm("v_cvt_pk_bf16_f32 %0, %1, %2" : "=v"(w.w) : "v"(u1.z), "v"(u1.w));
      const int r = sr + (j << 5);
      *(uint4*)&As[pn][(r << 6) + (slotA << 3)] = w;
    }
  };

  auto compute = [&](int p) {
    const ushort* Ab = &As[p][0];
    const ushort* Bb = &Bs[p][0];
#pragma unroll
    for (int ks = 0; ks < 2; ++ks) {
      const int kc = (ks << 2) + fq;  // chunk 0..7
      bf16x8_t af[4], bfr[4];
#pragma unroll
      for (int mi = 0; mi < 4; ++mi) {
        const int r = wr + (mi << 4) + fr;
        af[mi] = *(const bf16x8_t*)&Ab[(r << 6) + ((kc ^ (r & 7)) << 3)];
      }
#pragma unroll
      for (int ni = 0; ni < 4; ++ni) {
        const int r = wc + (ni << 4) + fr;
        bfr[ni] = *(const bf16x8_t*)&Bb[(r << 6) + ((kc ^ (r & 7)) << 3)];
      }
#pragma unroll
      for (int mi = 0; mi < 4; ++mi)
#pragma unroll
        for (int ni = 0; ni < 4; ++ni)
          acc[mi][ni] = __builtin_amdgcn_mfma_f32_16x16x32_bf16(af[mi], bfr[ni], acc[mi][ni], 0, 0, 0);
    }
  };

  // Prologue: stage tile 0 (A via regs+cvt, B via gload_lds), drain, barrier.
  loadA(0);
  issueB(0, 0);
  writeA(0);  // compiler waits vmcnt for av, leaves nothing critical behind
  asm volatile("s_waitcnt vmcnt(0) lgkmcnt(0)\n\ts_barrier" ::: "memory");

  for (int i = 0; i < 16; ++i) {
    const int p = i & 1;
    if (i < 15) {
      loadA((i + 1) << 6);        // 8 dwordx4 -> regs (issued early)
      issueB((i + 1) << 6, p ^ 1);
      // Newest in flight: 8 A + 4 B = 12. Retire exactly B(i).
      asm volatile("s_waitcnt vmcnt(12)\n\ts_barrier" ::: "memory");
    } else {
      asm volatile("s_waitcnt vmcnt(0)\n\ts_barrier" ::: "memory");
    }

    compute(p);

    if (i < 15) {
      writeA(p ^ 1);  // compiler vmcnt(4): A(i+1) done, B(i+1) stays in flight
      // A writes visible to all waves; all reads of buf p done.
      asm volatile("s_waitcnt lgkmcnt(0)\n\ts_barrier" ::: "memory");
    }
  }

  // Epilogue. C/D layout: col = lane&15, row = (lane>>4)*4 + reg.
#pragma unroll
  for (int mi = 0; mi < 4; ++mi) {
#pragma unroll
    for (int r = 0; r < 4; ++r) {
      const int row = m0 + wr + (mi << 4) + (fq << 2) + r;
      float* crow = C + (size_t)row * DDIM + n0 + wc + fr;
#pragma unroll
      for (int ni = 0; ni < 4; ++ni)
        crow[ni << 4] = acc[mi][ni][r];
    }
  }
}

// ---------------------------------------------------------------------------
// softmax over the size-1 sequence axis == 1.0 exactly -> out = x @ kernel[2].
// ---------------------------------------------------------------------------
extern "C" void kernel_launch(void* const* d_in, const int* in_sizes, int n_in,
                              void* d_out, int out_size, void* d_ws, size_t ws_size,
                              hipStream_t stream) {
  const float* x    = (const float*)d_in[0];
  const float* kern = (const float*)d_in[1];
  const float* W = kern + (size_t)2 * DDIM * DDIM;  // kernel[2] — V projection
  ushort* Wt = (ushort*)d_ws;                       // needs only 2 MiB of ws
  const int M = in_sizes[0] / DDIM;  // 8192

  transpose_w<<<dim3(DDIM / 64, DDIM / 64), 256, 0, stream>>>(W, Wt);
  gemm_fa<<<dim3(M / 128, DDIM / 128), 256, 0, stream>>>(x, Wt, (float*)d_out);
}